// Round 10
// baseline (185.611 us; speedup 1.0000x reference)
//
#include <hip/hip_runtime.h>
#include <math.h>

#define TLEN 4096
#define NB   1024
#define NS   10

// ---------------- KA: S partials + embedded k0 ------------------------------
// S[n,p,t] = sum_b SA[b,p,n]*x[t,b,n];  ps layout: ps[(sl*4096 + t)*100 + n*10+p]
#define TB   64    // t per block
#define BSL  128   // b per slice (8 slices)
#define BC   16    // b chunk staged in LDS
#define XSTR 166   // xs row stride (words); read lane-stride 6 mod 32 -> ~2-way

__device__ void k0_body(const float* __restrict__ adj, float* __restrict__ ck) {
  float Wm[5][5], L[5][5];
  for (int r = 0; r < 5; ++r)
    for (int c = 0; c < 5; ++c) Wm[r][c] = adj[r*5+c];
  for (int r = 0; r < 5; ++r) {
    float d = 0.f;
    for (int c = 0; c < 5; ++c) d += Wm[r][c];
    for (int c = 0; c < 5; ++c) L[r][c] = (r==c ? d : 0.f) - Wm[r][c];
  }
  float v[5] = {0.7f, -1.1f, 0.9f, -0.8f, 1.3f};
  for (int it = 0; it < 96; ++it) {
    float w[5];
    for (int r = 0; r < 5; ++r) {
      float s = 0.f;
      for (int c = 0; c < 5; ++c) s += L[r][c]*v[c];
      w[r] = s;
    }
    float s = fabsf(w[0])+fabsf(w[1])+fabsf(w[2])+fabsf(w[3])+fabsf(w[4]);
    float inv = 1.f/s;
    for (int r = 0; r < 5; ++r) v[r] = w[r]*inv;
  }
  float num = 0.f, den = 0.f;
  for (int r = 0; r < 5; ++r) {
    float s = 0.f;
    for (int c = 0; c < 5; ++c) s += L[r][c]*v[c];
    num += v[r]*s; den += v[r]*v[r];
  }
  const float lam = num/den;
  float Lt[5][5];
  for (int r = 0; r < 5; ++r)
    for (int c = 0; c < 5; ++c)
      Lt[r][c] = 2.f*L[r][c]/lam - (r==c ? 1.f : 0.f);
  float T2[5][5];
  for (int r = 0; r < 5; ++r)
    for (int c = 0; c < 5; ++c) {
      float s = 0.f;
      for (int j = 0; j < 5; ++j) s += Lt[r][j]*Lt[j][c];
      T2[r][c] = 2.f*s - (r==c ? 1.f : 0.f);
    }
  for (int p = 0; p < 10; ++p)
    for (int n = 0; n < 10; ++n) {
      int m = (10*p+n) % 25, r = m/5, c = m%5;
      ck[0*100 + p*10+n] = (r==c ? 1.f : 0.f);
      ck[1*100 + p*10+n] = Lt[r][c];
      ck[2*100 + p*10+n] = T2[r][c];
    }
}

__global__ __launch_bounds__(384) void ka_reduce(const float* __restrict__ x,
    const float* __restrict__ sa, const float* __restrict__ adj,
    float* __restrict__ ps, float* __restrict__ ck) {
  __shared__ __align__(16) float xs[TB*XSTR];     // 42.5 KB
  __shared__ __align__(16) float sas[BC*120];     // [bb][n][12] padded, 7.7 KB
  const int tid = threadIdx.x;
  if (tid >= 320) {                 // 6th wave: k0 in block (0,0), else exit
    if (tid == 320 && blockIdx.x == 0 && blockIdx.y == 0) k0_body(adj, ck);
    return;
  }
  const int n  = tid >> 5;          // 0..9
  const int h  = (tid >> 4) & 1;    // bb-half
  const int tg = tid & 15;          // t-group; owns t = tg + 16j, j=0..3
  const int t0 = blockIdx.x * TB;
  const int bbase = blockIdx.y * BSL;

  const int stt = tid / 40;          // 0..7
  const int sq  = tid - stt*40;      // 0..39
  int saw0[4], saw1[4];
  {
    #pragma unroll
    for (int e = 0; e < 4; ++e) {
      const int g = tid*4 + e, bb = g/100, r = g - bb*100, p = r/10, nn = r - p*10;
      saw0[e] = bb*120 + nn*12 + p;
    }
    #pragma unroll
    for (int e = 0; e < 4; ++e) {
      const int g = (tid+320)*4 + e, bb = g/100, r = g - bb*100, p = r/10, nn = r - p*10;
      saw1[e] = bb*120 + nn*12 + p;
    }
  }

  float acc[4][10];
  #pragma unroll
  for (int j = 0; j < 4; ++j)
    #pragma unroll
    for (int p = 0; p < 10; ++p) acc[j][p] = 0.f;

  for (int cch = 0; cch < BSL/BC; ++cch) {
    const int bch = bbase + cch*BC;
    // stage x[t0..t0+64][bch..bch+16][:] -> xs[t][bb*10+nn], 8 float4/thread
    #pragma unroll
    for (int r = 0; r < 8; ++r) {
      const int tt = stt + 8*r;
      const float4 v = *(const float4*)(x + (size_t)(t0+tt)*(NB*NS)
                                          + (size_t)bch*NS + sq*4);
      float2* w = (float2*)(xs + tt*XSTR + sq*4);
      w[0] = make_float2(v.x, v.y);
      w[1] = make_float2(v.z, v.w);
    }
    // stage SA[bch..bch+16][p][nn] -> sas[bb][nn][12]+p (transposed)
    {
      const float4 v = *(const float4*)(sa + (size_t)bch*100 + (size_t)tid*4);
      sas[saw0[0]] = v.x; sas[saw0[1]] = v.y;
      sas[saw0[2]] = v.z; sas[saw0[3]] = v.w;
      if (tid < 80) {
        const float4 v2 = *(const float4*)(sa + (size_t)bch*100 + (size_t)(tid+320)*4);
        sas[saw1[0]] = v2.x; sas[saw1[1]] = v2.y;
        sas[saw1[2]] = v2.z; sas[saw1[3]] = v2.w;
      }
    }
    __syncthreads();
    #pragma unroll
    for (int bb8 = 0; bb8 < 8; ++bb8) {
      const int bb = h*8 + bb8;
      const float* sp = sas + bb*120 + n*12;
      const float4 sA = *(const float4*)(sp);
      const float4 sB = *(const float4*)(sp + 4);
      const float2 sC = *(const float2*)(sp + 8);
      float xv[4];
      #pragma unroll
      for (int j = 0; j < 4; ++j)
        xv[j] = xs[(tg + 16*j)*XSTR + bb*NS + n];
      #pragma unroll
      for (int j = 0; j < 4; ++j) {
        acc[j][0] += sA.x*xv[j]; acc[j][1] += sA.y*xv[j];
        acc[j][2] += sA.z*xv[j]; acc[j][3] += sA.w*xv[j];
        acc[j][4] += sB.x*xv[j]; acc[j][5] += sB.y*xv[j];
        acc[j][6] += sB.z*xv[j]; acc[j][7] += sB.w*xv[j];
        acc[j][8] += sC.x*xv[j]; acc[j][9] += sC.y*xv[j];
      }
    }
    __syncthreads();
  }
  // cross-half reduction: h=1 parks partials in xs, h=0 adds and stores
  if (h) {
    float* d = xs + (n*16 + tg)*40;
    #pragma unroll
    for (int j = 0; j < 4; ++j)
      #pragma unroll
      for (int p = 0; p < 10; ++p) d[j*10+p] = acc[j][p];
  }
  __syncthreads();
  if (!h) {
    const float* d = xs + (n*16 + tg)*40;
    #pragma unroll
    for (int j = 0; j < 4; ++j) {
      float* o = ps + ((size_t)blockIdx.y*TLEN + t0 + tg + 16*j)*100 + n*10;
      #pragma unroll
      for (int p = 0; p < 10; ++p) o[p] = acc[j][p] + d[j*10+p];
    }
  }
}

// ---------------- KC: out[t,b,n] = relu( sum_p S[n,p,t] * W[p,n,b] ) -------
#define TT 8
__global__ __launch_bounds__(256) void kc_out(const float* __restrict__ theta,
    const float* __restrict__ ck, const float* __restrict__ ps,
    float* __restrict__ out) {
  __shared__ __align__(16) float S[TT*120];     // [tt][n][12] padded
  __shared__ float C[300];
  __shared__ __align__(16) float stg[2][2560];  // double-buffered store stage
  const int tid = threadIdx.x;
  const int t0 = blockIdx.x * TT;
  const int b  = blockIdx.y * 256 + tid;
  for (int j = tid; j < 300; j += 256) C[j] = ck[j];
  for (int j = tid; j < TT*100; j += 256) {
    const int tt = j / 100, q = j - tt*100;
    float s = 0.f;
    #pragma unroll
    for (int sl = 0; sl < 8; ++sl)
      s += ps[((size_t)sl*TLEN + (t0+tt))*100 + q];
    S[tt*120 + (q/10)*12 + (q - (q/10)*10)] = s;
  }
  __syncthreads();
  float W[10][10];
  #pragma unroll
  for (int p = 0; p < 10; ++p) {
    const float th0 = theta[          p*NB + b];
    const float th1 = theta[10*NB  +  p*NB + b];
    const float th2 = theta[20*NB  +  p*NB + b];
    #pragma unroll
    for (int nn = 0; nn < 10; ++nn)
      W[p][nn] = C[p*10+nn]*th0 + C[100+p*10+nn]*th1 + C[200+p*10+nn]*th2;
  }
  for (int tt = 0; tt < TT; ++tt) {
    float acc[10];
    #pragma unroll
    for (int nn = 0; nn < 10; ++nn) {
      const float4 s0 = *(const float4*)(S + tt*120 + nn*12);
      const float4 s1 = *(const float4*)(S + tt*120 + nn*12 + 4);
      const float2 s2 = *(const float2*)(S + tt*120 + nn*12 + 8);
      acc[nn] = s0.x*W[0][nn] + s0.y*W[1][nn] + s0.z*W[2][nn] + s0.w*W[3][nn]
              + s1.x*W[4][nn] + s1.y*W[5][nn] + s1.z*W[6][nn] + s1.w*W[7][nn]
              + s2.x*W[8][nn] + s2.y*W[9][nn];
    }
    float* sg = stg[tt & 1];
    #pragma unroll
    for (int nn = 0; nn < 10; ++nn)
      sg[tid*10 + nn] = fmaxf(acc[nn], 0.f);
    __syncthreads();
    const float4* sp = (const float4*)sg;
    float4* op = (float4*)(out + (size_t)(t0+tt)*(NB*NS)
                               + (size_t)blockIdx.y*2560);
    op[tid]       = sp[tid];
    op[tid + 256] = sp[tid + 256];
    if (tid < 128) op[tid + 512] = sp[tid + 512];
  }
}

extern "C" void kernel_launch(void* const* d_in, const int* in_sizes, int n_in,
                              void* d_out, int out_size, void* d_ws, size_t ws_size,
                              hipStream_t stream) {
  const float* x   = (const float*)d_in[0];  // (4096,1024,10)
  const float* adj = (const float*)d_in[1];  // (5,5)
  const float* sa  = (const float*)d_in[2];  // (1024,10,10)
  const float* th  = (const float*)d_in[3];  // (3,10,1024)
  float* out = (float*)d_out;
  float* ws  = (float*)d_ws;
  float* ck  = ws;                // 300 floats
  float* ps  = ws + 1024;         // 8*4096*100 floats = 13.1 MB
  // MEASUREMENT ROUND 2: ka x2 + kc x2 (idempotent, deterministic).
  //   kc marginal = new_total - 150.8 (R9);  ka marginal = 43.6 (R9).
  // Revert to single launches next round, targeting whichever dominates.
  hipLaunchKernelGGL(ka_reduce, dim3(TLEN/TB, 8), dim3(384), 0, stream,
                     x, sa, adj, ps, ck);
  hipLaunchKernelGGL(ka_reduce, dim3(TLEN/TB, 8), dim3(384), 0, stream,
                     x, sa, adj, ps, ck);
  hipLaunchKernelGGL(kc_out,    dim3(TLEN/TT, NB/256), dim3(256), 0, stream,
                     th, ck, ps, out);
  hipLaunchKernelGGL(kc_out,    dim3(TLEN/TT, NB/256), dim3(256), 0, stream,
                     th, ck, ps, out);
}

// Round 11
// 99.125 us; speedup vs baseline: 1.8725x; 1.8725x over previous
//
#include <hip/hip_runtime.h>
#include <math.h>

#define TLEN 4096
#define NB   1024
#define NS   10

typedef __attribute__((ext_vector_type(8))) short  s16x8;
typedef __attribute__((ext_vector_type(4))) float  f32x4;

__device__ void k0_body(const float* __restrict__ adj, float* __restrict__ ck) {
  float Wm[5][5], L[5][5];
  for (int r = 0; r < 5; ++r)
    for (int c = 0; c < 5; ++c) Wm[r][c] = adj[r*5+c];
  for (int r = 0; r < 5; ++r) {
    float d = 0.f;
    for (int c = 0; c < 5; ++c) d += Wm[r][c];
    for (int c = 0; c < 5; ++c) L[r][c] = (r==c ? d : 0.f) - Wm[r][c];
  }
  float v[5] = {0.7f, -1.1f, 0.9f, -0.8f, 1.3f};
  for (int it = 0; it < 96; ++it) {
    float w[5];
    for (int r = 0; r < 5; ++r) {
      float s = 0.f;
      for (int c = 0; c < 5; ++c) s += L[r][c]*v[c];
      w[r] = s;
    }
    float s = fabsf(w[0])+fabsf(w[1])+fabsf(w[2])+fabsf(w[3])+fabsf(w[4]);
    float inv = 1.f/s;
    for (int r = 0; r < 5; ++r) v[r] = w[r]*inv;
  }
  float num = 0.f, den = 0.f;
  for (int r = 0; r < 5; ++r) {
    float s = 0.f;
    for (int c = 0; c < 5; ++c) s += L[r][c]*v[c];
    num += v[r]*s; den += v[r]*v[r];
  }
  const float lam = num/den;
  float Lt[5][5];
  for (int r = 0; r < 5; ++r)
    for (int c = 0; c < 5; ++c)
      Lt[r][c] = 2.f*L[r][c]/lam - (r==c ? 1.f : 0.f);
  float T2[5][5];
  for (int r = 0; r < 5; ++r)
    for (int c = 0; c < 5; ++c) {
      float s = 0.f;
      for (int j = 0; j < 5; ++j) s += Lt[r][j]*Lt[j][c];
      T2[r][c] = 2.f*s - (r==c ? 1.f : 0.f);
    }
  for (int p = 0; p < 10; ++p)
    for (int n = 0; n < 10; ++n) {
      int m = (10*p+n) % 25, r = m/5, c = m%5;
      ck[0*100 + p*10+n] = (r==c ? 1.f : 0.f);
      ck[1*100 + p*10+n] = Lt[r][c];
      ck[2*100 + p*10+n] = T2[r][c];
    }
}

static __device__ __forceinline__ unsigned bfu(float f) {
  unsigned u = __float_as_uint(f);
  return (u + 0x7FFFu + ((u >> 16) & 1u)) >> 16;   // RNE bf16
}
static __device__ __forceinline__ unsigned pk2(float lo, float hi) {
  return bfu(lo) | (bfu(hi) << 16);
}

// ---------------- KA (MFMA): ps[(hf*4096 + t)*100 + n*10+p] ----------------
// S_n[p,t] = sum_b SA[b,p,n] * x[t,b,n]  via mfma_f32_16x16x32_bf16.
// LDS layout (fragment-ready): plane(n,ks) of 64 lanes x 8 bf16:
//   idx = ((n*4+ks)*64 + L)*8 + j ; A: L = kg*16 + p, B: L = kg*16 + tl;
//   k = ks*32 + kg*8 + j.
#define KC   128
#define NCHK 4
#define XB_U32 10240   // 10n*4ks*64*8 bf16 /2

__global__ __launch_bounds__(384) void ka_mfma(
    const float* __restrict__ x, const float* __restrict__ sa,
    const float* __restrict__ adj, float* __restrict__ ps,
    float* __restrict__ ck) {
  __shared__ __align__(16) unsigned lds[2*XB_U32];   // XB | AS, 80 KB
  unsigned* XB = lds;
  unsigned* AS = lds + XB_U32;
  const int tid = threadIdx.x;
  if (tid >= 320) {
    if (tid == 320 && blockIdx.x == 0 && blockIdx.y == 0) k0_body(adj, ck);
    return;
  }
  const int w    = tid >> 6;       // wave 0..4 -> n pair
  const int l    = tid & 63;
  const int tl16 = l & 15;
  const int t0   = blockIdx.x * 16;
  const int b0   = blockIdx.y * 512;
  const int n0   = 2*w, n1 = 2*w + 1;

  // x staging geometry (constant per thread): bp = b-pair, g = n (even)
  const int xbp = tid / 5;               // 0..63
  const int xg  = (tid - xbp*5) * 2;     // 0,2,4,6,8
  const int xk  = 2*xbp;
  const int xks = xk >> 5, xkg = (xk & 31) >> 3, xj = xk & 7;
  const int xbase0 = ((xg*4 + xks)*64 + xkg*16)*4 + (xj >> 1);  // + tl*4

  f32x4 acc0 = {0.f,0.f,0.f,0.f}, acc1 = {0.f,0.f,0.f,0.f};

  for (int c = 0; c < NCHK; ++c) {
    const int bc = b0 + c*KC;
    // ---- stage x[t0..16][bc..bc+128][10] -> XB (bf16 pairs along k)
    {
      const float* gp0 = x + (size_t)t0*(NB*NS) + (size_t)bc*NS + xbp*20 + xg;
      #pragma unroll
      for (int r = 0; r < 16; ++r) {        // r = t-local
        const float* gp = gp0 + (size_t)r*(NB*NS);
        const float2 lo = *(const float2*)(gp);
        const float2 hi = *(const float2*)(gp + NS);
        const int base = xbase0 + r*4;
        XB[base]        = pk2(lo.x, hi.x);  // n = xg
        XB[base + 1024] = pk2(lo.y, hi.y);  // n = xg+1
      }
    }
    // ---- stage SA[bc..bc+128][p][n] -> AS
    #pragma unroll
    for (int r = 0; r < 10; ++r) {
      const int s  = tid + 320*r;          // 0..3199
      const int bp = s / 50;
      const int g  = (s - bp*50) * 2;      // 0..98 even
      const int p  = g / 10, n = g - p*10; // n even
      const int k  = 2*bp;
      const float* gp = sa + (size_t)(bc + k)*100 + g;
      const float2 lo = *(const float2*)(gp);
      const float2 hi = *(const float2*)(gp + 100);
      const int ks = k >> 5, kg = (k & 31) >> 3, j = k & 7;
      const int base = ((n*4 + ks)*64 + kg*16 + p)*4 + (j >> 1);
      AS[base]        = pk2(lo.x, hi.x);   // n
      AS[base + 1024] = pk2(lo.y, hi.y);   // n+1
    }
    __syncthreads();
    // ---- MFMA: 4 k-steps x 2 n ; frag reads lane-linear (conflict-free)
    const s16x8* XBf = (const s16x8*)XB;
    const s16x8* ASf = (const s16x8*)AS;
    #pragma unroll
    for (int ks = 0; ks < 4; ++ks) {
      const s16x8 a0 = ASf[(n0*4 + ks)*64 + l];
      const s16x8 bb0 = XBf[(n0*4 + ks)*64 + l];
      acc0 = __builtin_amdgcn_mfma_f32_16x16x32_bf16(a0, bb0, acc0, 0, 0, 0);
      const s16x8 a1 = ASf[(n1*4 + ks)*64 + l];
      const s16x8 bb1 = XBf[(n1*4 + ks)*64 + l];
      acc1 = __builtin_amdgcn_mfma_f32_16x16x32_bf16(a1, bb1, acc1, 0, 0, 0);
    }
    __syncthreads();
  }
  // ---- C layout (m89): col = lane&15 (t), row = (lane>>4)*4 + reg (p)
  const int pg = (l >> 4) * 4;
  float* pd = ps + ((size_t)blockIdx.y*TLEN + t0 + tl16)*100;
  #pragma unroll
  for (int r = 0; r < 4; ++r) {
    const int p = pg + r;
    if (p < 10) {
      pd[n0*10 + p] = acc0[r];
      pd[n1*10 + p] = acc1[r];
    }
  }
}

// ---------------- KC: out[t,b,n] = relu( sum_p S[n,p,t] * W[p,n,b] ) -------
#define TT 8
__global__ __launch_bounds__(256) void kc_out(const float* __restrict__ theta,
    const float* __restrict__ ck, const float* __restrict__ ps,
    float* __restrict__ out) {
  __shared__ __align__(16) float S[TT*120];     // [tt][n][12] padded
  __shared__ float C[300];
  __shared__ __align__(16) float stg[2][2560];  // double-buffered store stage
  const int tid = threadIdx.x;
  const int t0 = blockIdx.x * TT;
  const int b  = blockIdx.y * 256 + tid;
  for (int j = tid; j < 300; j += 256) C[j] = ck[j];
  for (int j = tid; j < TT*100; j += 256) {
    const int tt = j / 100, q = j - tt*100;
    float s = 0.f;
    #pragma unroll
    for (int sl = 0; sl < 2; ++sl)
      s += ps[((size_t)sl*TLEN + (t0+tt))*100 + q];
    S[tt*120 + (q/10)*12 + (q - (q/10)*10)] = s;
  }
  __syncthreads();
  float W[10][10];
  #pragma unroll
  for (int p = 0; p < 10; ++p) {
    const float th0 = theta[          p*NB + b];
    const float th1 = theta[10*NB  +  p*NB + b];
    const float th2 = theta[20*NB  +  p*NB + b];
    #pragma unroll
    for (int nn = 0; nn < 10; ++nn)
      W[p][nn] = C[p*10+nn]*th0 + C[100+p*10+nn]*th1 + C[200+p*10+nn]*th2;
  }
  for (int tt = 0; tt < TT; ++tt) {
    float acc[10];
    #pragma unroll
    for (int nn = 0; nn < 10; ++nn) {
      const float4 s0 = *(const float4*)(S + tt*120 + nn*12);
      const float4 s1 = *(const float4*)(S + tt*120 + nn*12 + 4);
      const float2 s2 = *(const float2*)(S + tt*120 + nn*12 + 8);
      acc[nn] = s0.x*W[0][nn] + s0.y*W[1][nn] + s0.z*W[2][nn] + s0.w*W[3][nn]
              + s1.x*W[4][nn] + s1.y*W[5][nn] + s1.z*W[6][nn] + s1.w*W[7][nn]
              + s2.x*W[8][nn] + s2.y*W[9][nn];
    }
    float* sg = stg[tt & 1];
    #pragma unroll
    for (int nn = 0; nn < 10; ++nn)
      sg[tid*10 + nn] = fmaxf(acc[nn], 0.f);
    __syncthreads();
    const float4* sp = (const float4*)sg;
    float4* op = (float4*)(out + (size_t)(t0+tt)*(NB*NS)
                               + (size_t)blockIdx.y*2560);
    op[tid]       = sp[tid];
    op[tid + 256] = sp[tid + 256];
    if (tid < 128) op[tid + 512] = sp[tid + 512];
  }
}

extern "C" void kernel_launch(void* const* d_in, const int* in_sizes, int n_in,
                              void* d_out, int out_size, void* d_ws, size_t ws_size,
                              hipStream_t stream) {
  const float* x   = (const float*)d_in[0];  // (4096,1024,10)
  const float* adj = (const float*)d_in[1];  // (5,5)
  const float* sa  = (const float*)d_in[2];  // (1024,10,10)
  const float* th  = (const float*)d_in[3];  // (3,10,1024)
  float* out = (float*)d_out;
  float* ws  = (float*)d_ws;
  float* ck  = ws;                // 300 floats
  float* ps  = ws + 1024;         // 2*4096*100 floats = 3.3 MB
  hipLaunchKernelGGL(ka_mfma, dim3(TLEN/16, 2), dim3(384), 0, stream,
                     x, sa, adj, ps, ck);
  hipLaunchKernelGGL(kc_out,  dim3(TLEN/TT, NB/256), dim3(256), 0, stream,
                     th, ck, ps, out);
}

// Round 12
// 98.501 us; speedup vs baseline: 1.8844x; 1.0063x over previous
//
#include <hip/hip_runtime.h>
#include <math.h>

#define TLEN 4096
#define NB   1024
#define NS   10

typedef __attribute__((ext_vector_type(8))) short  s16x8;
typedef __attribute__((ext_vector_type(4))) float  f32x4;

__device__ void k0_body(const float* __restrict__ adj, float* __restrict__ ck) {
  float Wm[5][5], L[5][5];
  for (int r = 0; r < 5; ++r)
    for (int c = 0; c < 5; ++c) Wm[r][c] = adj[r*5+c];
  for (int r = 0; r < 5; ++r) {
    float d = 0.f;
    for (int c = 0; c < 5; ++c) d += Wm[r][c];
    for (int c = 0; c < 5; ++c) L[r][c] = (r==c ? d : 0.f) - Wm[r][c];
  }
  float v[5] = {0.7f, -1.1f, 0.9f, -0.8f, 1.3f};
  for (int it = 0; it < 96; ++it) {
    float w[5];
    for (int r = 0; r < 5; ++r) {
      float s = 0.f;
      for (int c = 0; c < 5; ++c) s += L[r][c]*v[c];
      w[r] = s;
    }
    float s = fabsf(w[0])+fabsf(w[1])+fabsf(w[2])+fabsf(w[3])+fabsf(w[4]);
    float inv = 1.f/s;
    for (int r = 0; r < 5; ++r) v[r] = w[r]*inv;
  }
  float num = 0.f, den = 0.f;
  for (int r = 0; r < 5; ++r) {
    float s = 0.f;
    for (int c = 0; c < 5; ++c) s += L[r][c]*v[c];
    num += v[r]*s; den += v[r]*v[r];
  }
  const float lam = num/den;
  float Lt[5][5];
  for (int r = 0; r < 5; ++r)
    for (int c = 0; c < 5; ++c)
      Lt[r][c] = 2.f*L[r][c]/lam - (r==c ? 1.f : 0.f);
  float T2[5][5];
  for (int r = 0; r < 5; ++r)
    for (int c = 0; c < 5; ++c) {
      float s = 0.f;
      for (int j = 0; j < 5; ++j) s += Lt[r][j]*Lt[j][c];
      T2[r][c] = 2.f*s - (r==c ? 1.f : 0.f);
    }
  for (int p = 0; p < 10; ++p)
    for (int n = 0; n < 10; ++n) {
      int m = (10*p+n) % 25, r = m/5, c = m%5;
      ck[0*100 + p*10+n] = (r==c ? 1.f : 0.f);
      ck[1*100 + p*10+n] = Lt[r][c];
      ck[2*100 + p*10+n] = T2[r][c];
    }
}

static __device__ __forceinline__ unsigned cvtpk(float lo, float hi) {
  unsigned r;
  asm("v_cvt_pk_bf16_f32 %0, %1, %2" : "=v"(r) : "v"(lo), "v"(hi));
  return r;
}
// f4-unit index of (plane P, lane-slot L), XOR-swizzled for write-bank spread
static __device__ __forceinline__ int swz(int P, int L) {
  return P*64 + (L ^ ((P ^ (P >> 2)) & 7));
}

// ---------------- KA (MFMA, dbuf): ps[(hf*4096 + t)*100 + n*10+p] ----------
// S_n[p,t] = sum_b SA[b,p,n]*x[t,b,n] via mfma_f32_16x16x32_bf16, KC=64/chunk.
// Plane (n,ks): 64 lanes x 8 bf16; A: L=kg*16+p, B: L=kg*16+tl; k=ks*32+kg*8+j.
#define KC 64
#define BUF_U32 10240   // XB 5120 | AS 5120

__global__ __launch_bounds__(384, 3) void ka_mfma(
    const float* __restrict__ x, const float* __restrict__ sa,
    const float* __restrict__ adj, float* __restrict__ ps,
    float* __restrict__ ck) {
  __shared__ __align__(16) unsigned lds[2*BUF_U32];   // 80 KB
  const int tid = threadIdx.x;
  if (tid >= 320) {
    if (tid == 320 && blockIdx.x == 0 && blockIdx.y == 0) k0_body(adj, ck);
    return;
  }
  const int w  = tid >> 6;          // wave -> n pair
  const int l  = tid & 63;
  const int t0 = blockIdx.x * 16;
  const int b0 = blockIdx.y * 512;
  const int n0 = 2*w, n1 = 2*w + 1;

  // staging geometry (x): tid = bp*10 + q*2 + th
  const int bp = tid / 10;
  const int rm = tid - bp*10;
  const int q  = rm >> 1;           // n pair
  const int th = rm & 1;            // t half
  // SA: same bp, gq = rm (p = gq? no: p = gq below), thread owns g=gq*10+2e
  const int gq = rm;
  // shared k decomposition for k-pair (2bp, 2bp+1)
  const int ksx = bp >> 4;
  const int kgx = (bp & 15) >> 2;
  const int jwx = bp & 3;

  f32x4 acc0 = {0.f,0.f,0.f,0.f}, acc1 = {0.f,0.f,0.f,0.f};
  float2 xlo[8], xhi[8], slo[5], shi[5];

  unsigned* cur = lds;
  unsigned* nxt = lds + BUF_U32;

  // ---- load chunk 0
  {
    const float* xb = x + (size_t)(t0 + th*8)*(NB*NS) + (size_t)(b0 + 2*bp)*NS + 2*q;
    #pragma unroll
    for (int r = 0; r < 8; ++r) {
      xlo[r] = *(const float2*)(xb + r*(NB*NS));
      xhi[r] = *(const float2*)(xb + r*(NB*NS) + NS);
    }
    const float* sb = sa + (size_t)(b0 + 2*bp)*100 + gq*10;
    #pragma unroll
    for (int e = 0; e < 5; ++e) {
      slo[e] = *(const float2*)(sb + 2*e);
      shi[e] = *(const float2*)(sb + 100 + 2*e);
    }
  }
  // ---- pack+write chunk 0 -> cur
  #pragma unroll
  for (int r = 0; r < 8; ++r) {
    const int L = kgx*16 + th*8 + r;
    cur[swz((2*q  )*2 + ksx, L)*4 + jwx] = cvtpk(xlo[r].x, xhi[r].x);
    cur[swz((2*q+1)*2 + ksx, L)*4 + jwx] = cvtpk(xlo[r].y, xhi[r].y);
  }
  #pragma unroll
  for (int e = 0; e < 5; ++e) {
    const int L = kgx*16 + gq;      // p = gq
    cur[5120 + swz((2*e  )*2 + ksx, L)*4 + jwx] = cvtpk(slo[e].x, shi[e].x);
    cur[5120 + swz((2*e+1)*2 + ksx, L)*4 + jwx] = cvtpk(slo[e].y, shi[e].y);
  }

  for (int c = 0; c < 8; ++c) {
    __syncthreads();
    // issue next chunk's loads early (fly across MFMA + write phase)
    if (c < 7) {
      const int bc = b0 + (c+1)*KC;
      const float* xb = x + (size_t)(t0 + th*8)*(NB*NS) + (size_t)(bc + 2*bp)*NS + 2*q;
      #pragma unroll
      for (int r = 0; r < 8; ++r) {
        xlo[r] = *(const float2*)(xb + r*(NB*NS));
        xhi[r] = *(const float2*)(xb + r*(NB*NS) + NS);
      }
      const float* sb = sa + (size_t)(bc + 2*bp)*100 + gq*10;
      #pragma unroll
      for (int e = 0; e < 5; ++e) {
        slo[e] = *(const float2*)(sb + 2*e);
        shi[e] = *(const float2*)(sb + 100 + 2*e);
      }
    }
    // MFMA from cur (frag reads lane-bijective per plane)
    {
      const s16x8* XBf = (const s16x8*)cur;
      const s16x8* ASf = (const s16x8*)(cur + 5120);
      #pragma unroll
      for (int ks = 0; ks < 2; ++ks) {
        acc0 = __builtin_amdgcn_mfma_f32_16x16x32_bf16(
                 ASf[swz(n0*2+ks, l)], XBf[swz(n0*2+ks, l)], acc0, 0, 0, 0);
        acc1 = __builtin_amdgcn_mfma_f32_16x16x32_bf16(
                 ASf[swz(n1*2+ks, l)], XBf[swz(n1*2+ks, l)], acc1, 0, 0, 0);
      }
    }
    // pack+write chunk c+1 -> nxt, swap
    if (c < 7) {
      #pragma unroll
      for (int r = 0; r < 8; ++r) {
        const int L = kgx*16 + th*8 + r;
        nxt[swz((2*q  )*2 + ksx, L)*4 + jwx] = cvtpk(xlo[r].x, xhi[r].x);
        nxt[swz((2*q+1)*2 + ksx, L)*4 + jwx] = cvtpk(xlo[r].y, xhi[r].y);
      }
      #pragma unroll
      for (int e = 0; e < 5; ++e) {
        const int L = kgx*16 + gq;
        nxt[5120 + swz((2*e  )*2 + ksx, L)*4 + jwx] = cvtpk(slo[e].x, shi[e].x);
        nxt[5120 + swz((2*e+1)*2 + ksx, L)*4 + jwx] = cvtpk(slo[e].y, shi[e].y);
      }
      unsigned* t = cur; cur = nxt; nxt = t;
    }
  }
  // C layout: col = lane&15 (t), row = (lane>>4)*4 + reg (p)
  const int pg = (l >> 4) * 4;
  float* pd = ps + ((size_t)blockIdx.y*TLEN + t0 + (l & 15))*100;
  #pragma unroll
  for (int r = 0; r < 4; ++r) {
    const int p = pg + r;
    if (p < 10) {
      pd[n0*10 + p] = acc0[r];
      pd[n1*10 + p] = acc1[r];
    }
  }
}

// ---------------- KC: out[t,b,n] = relu( sum_p S[n,p,t] * W[p,n,b] ) -------
#define TT 8
__global__ __launch_bounds__(256) void kc_out(const float* __restrict__ theta,
    const float* __restrict__ ck, const float* __restrict__ ps,
    float* __restrict__ out) {
  __shared__ __align__(16) float S[TT*120];     // [tt][n][12] padded
  __shared__ float C[300];
  __shared__ __align__(16) float stg[2][2560];  // double-buffered store stage
  const int tid = threadIdx.x;
  const int t0 = blockIdx.x * TT;
  const int b  = blockIdx.y * 256 + tid;
  for (int j = tid; j < 300; j += 256) C[j] = ck[j];
  for (int j = tid; j < TT*100; j += 256) {
    const int tt = j / 100, q = j - tt*100;
    float s = 0.f;
    #pragma unroll
    for (int sl = 0; sl < 2; ++sl)
      s += ps[((size_t)sl*TLEN + (t0+tt))*100 + q];
    S[tt*120 + (q/10)*12 + (q - (q/10)*10)] = s;
  }
  __syncthreads();
  float W[10][10];
  #pragma unroll
  for (int p = 0; p < 10; ++p) {
    const float th0 = theta[          p*NB + b];
    const float th1 = theta[10*NB  +  p*NB + b];
    const float th2 = theta[20*NB  +  p*NB + b];
    #pragma unroll
    for (int nn = 0; nn < 10; ++nn)
      W[p][nn] = C[p*10+nn]*th0 + C[100+p*10+nn]*th1 + C[200+p*10+nn]*th2;
  }
  for (int tt = 0; tt < TT; ++tt) {
    float acc[10];
    #pragma unroll
    for (int nn = 0; nn < 10; ++nn) {
      const float4 s0 = *(const float4*)(S + tt*120 + nn*12);
      const float4 s1 = *(const float4*)(S + tt*120 + nn*12 + 4);
      const float2 s2 = *(const float2*)(S + tt*120 + nn*12 + 8);
      acc[nn] = s0.x*W[0][nn] + s0.y*W[1][nn] + s0.z*W[2][nn] + s0.w*W[3][nn]
              + s1.x*W[4][nn] + s1.y*W[5][nn] + s1.z*W[6][nn] + s1.w*W[7][nn]
              + s2.x*W[8][nn] + s2.y*W[9][nn];
    }
    float* sg = stg[tt & 1];
    #pragma unroll
    for (int nn = 0; nn < 10; ++nn)
      sg[tid*10 + nn] = fmaxf(acc[nn], 0.f);
    __syncthreads();
    const float4* sp = (const float4*)sg;
    float4* op = (float4*)(out + (size_t)(t0+tt)*(NB*NS)
                               + (size_t)blockIdx.y*2560);
    op[tid]       = sp[tid];
    op[tid + 256] = sp[tid + 256];
    if (tid < 128) op[tid + 512] = sp[tid + 512];
  }
}

extern "C" void kernel_launch(void* const* d_in, const int* in_sizes, int n_in,
                              void* d_out, int out_size, void* d_ws, size_t ws_size,
                              hipStream_t stream) {
  const float* x   = (const float*)d_in[0];  // (4096,1024,10)
  const float* adj = (const float*)d_in[1];  // (5,5)
  const float* sa  = (const float*)d_in[2];  // (1024,10,10)
  const float* th  = (const float*)d_in[3];  // (3,10,1024)
  float* out = (float*)d_out;
  float* ws  = (float*)d_ws;
  float* ck  = ws;                // 300 floats
  float* ps  = ws + 1024;         // 2*4096*100 floats = 3.3 MB
  hipLaunchKernelGGL(ka_mfma, dim3(TLEN/16, 2), dim3(384), 0, stream,
                     x, sa, adj, ps, ck);
  hipLaunchKernelGGL(kc_out,  dim3(TLEN/TT, NB/256), dim3(256), 0, stream,
                     th, ck, ps, out);
}

// Round 13
// 85.243 us; speedup vs baseline: 2.1775x; 1.1555x over previous
//
#include <hip/hip_runtime.h>
#include <math.h>

#define TLEN 4096
#define NB   1024
#define NS   10
#define KC   64
#define NCHK 16
#define BUF_U32 10240   // XB 5120 | AS 5120 (u32 units, 40 KB)

typedef __attribute__((ext_vector_type(8))) short s16x8;
typedef __attribute__((ext_vector_type(4))) float f32x4;
typedef __attribute__((ext_vector_type(2))) float f32x2;

static __device__ __forceinline__ unsigned cvtpk(float lo, float hi) {
  unsigned r;
  asm("v_cvt_pk_bf16_f32 %0, %1, %2" : "=v"(r) : "v"(lo), "v"(hi));
  return r;
}
static __device__ __forceinline__ int swz(int P, int L) {
  return P*64 + (L ^ ((P ^ (P >> 2)) & 7));
}

// Fused: per block (t-tile of 16), S[n,p,t] = sum_b SA[b,p,n]*x[t,b,n] via
// MFMA over 16 K-chunks; then out[t,b,n] = relu(sum_p S * W[p,n,b]).
// Laplacian power-iteration runs on tid 320, 8 iters/chunk (hidden).
__global__ __launch_bounds__(512) void fused_k(
    const float* __restrict__ x, const float* __restrict__ sa,
    const float* __restrict__ adj, const float* __restrict__ theta,
    float* __restrict__ out) {
  __shared__ __align__(16) unsigned buf[BUF_U32];   // 40 KB; phase2: stg
  __shared__ __align__(16) float S[16*120];         // [t][n][12] padded
  __shared__ float ck[300];
  const int tid = threadIdx.x;
  const int l   = tid & 63;
  const int t0  = blockIdx.x * 16;

  // ---- phase-1 geometry (valid for tid<320): tid = bp*10 + q*2 + th
  const int w   = tid >> 6;
  const int bp  = tid / 10;
  const int rm  = tid - bp*10;
  const int q   = rm >> 1;
  const int th  = rm & 1;
  const int gq  = rm;
  const int ksx = bp >> 4;
  const int kgx = (bp & 15) >> 2;
  const int jwx = bp & 3;
  const int n0  = 2*w, n1 = 2*w + 1;

  f32x4 acc0 = {0.f,0.f,0.f,0.f}, acc1 = {0.f,0.f,0.f,0.f};
  f32x2 xlo[8], xhi[8], slo[5], shi[5];

  // ---- k0 state (tid 320 only uses it)
  float pL[5][5], pv[5];
  if (tid == 320) {
    float Wm[5][5];
    #pragma unroll
    for (int r = 0; r < 5; ++r)
      #pragma unroll
      for (int c = 0; c < 5; ++c) Wm[r][c] = adj[r*5+c];
    #pragma unroll
    for (int r = 0; r < 5; ++r) {
      float d = 0.f;
      #pragma unroll
      for (int c = 0; c < 5; ++c) d += Wm[r][c];
      #pragma unroll
      for (int c = 0; c < 5; ++c) pL[r][c] = (r==c ? d : 0.f) - Wm[r][c];
    }
    pv[0]=0.7f; pv[1]=-1.1f; pv[2]=0.9f; pv[3]=-0.8f; pv[4]=1.3f;
  }

  // ---- prologue: load + stage chunk 0
  if (tid < 320) {
    const float* xb = x + (size_t)(t0 + th*8)*(NB*NS) + (size_t)(2*bp)*NS + 2*q;
    #pragma unroll
    for (int r = 0; r < 8; ++r) {
      xlo[r] = __builtin_nontemporal_load((const f32x2*)(xb + r*(NB*NS)));
      xhi[r] = __builtin_nontemporal_load((const f32x2*)(xb + r*(NB*NS) + NS));
    }
    const float* sb = sa + (size_t)(2*bp)*100 + gq*10;
    #pragma unroll
    for (int e = 0; e < 5; ++e) {
      slo[e] = *(const f32x2*)(sb + 2*e);
      shi[e] = *(const f32x2*)(sb + 100 + 2*e);
    }
    #pragma unroll
    for (int r = 0; r < 8; ++r) {
      const int L = kgx*16 + th*8 + r;
      buf[swz((2*q  )*2 + ksx, L)*4 + jwx] = cvtpk(xlo[r].x, xhi[r].x);
      buf[swz((2*q+1)*2 + ksx, L)*4 + jwx] = cvtpk(xlo[r].y, xhi[r].y);
    }
    #pragma unroll
    for (int e = 0; e < 5; ++e) {
      const int L = kgx*16 + gq;
      buf[5120 + swz((2*e  )*2 + ksx, L)*4 + jwx] = cvtpk(slo[e].x, shi[e].x);
      buf[5120 + swz((2*e+1)*2 + ksx, L)*4 + jwx] = cvtpk(slo[e].y, shi[e].y);
    }
  }

  for (int c = 0; c < NCHK; ++c) {
    __syncthreads();                       // staged writes visible
    if (tid < 320) {
      if (c + 1 < NCHK) {                  // issue next chunk's loads early
        const int bc = (c+1)*KC;
        const float* xb = x + (size_t)(t0 + th*8)*(NB*NS)
                            + (size_t)(bc + 2*bp)*NS + 2*q;
        #pragma unroll
        for (int r = 0; r < 8; ++r) {
          xlo[r] = __builtin_nontemporal_load((const f32x2*)(xb + r*(NB*NS)));
          xhi[r] = __builtin_nontemporal_load((const f32x2*)(xb + r*(NB*NS) + NS));
        }
        const float* sb = sa + (size_t)(bc + 2*bp)*100 + gq*10;
        #pragma unroll
        for (int e = 0; e < 5; ++e) {
          slo[e] = *(const f32x2*)(sb + 2*e);
          shi[e] = *(const f32x2*)(sb + 100 + 2*e);
        }
      }
      const s16x8* XBf = (const s16x8*)buf;
      const s16x8* ASf = (const s16x8*)(buf + 5120);
      #pragma unroll
      for (int ks = 0; ks < 2; ++ks) {
        acc0 = __builtin_amdgcn_mfma_f32_16x16x32_bf16(
                 ASf[swz(n0*2+ks, l)], XBf[swz(n0*2+ks, l)], acc0, 0, 0, 0);
        acc1 = __builtin_amdgcn_mfma_f32_16x16x32_bf16(
                 ASf[swz(n1*2+ks, l)], XBf[swz(n1*2+ks, l)], acc1, 0, 0, 0);
      }
    } else if (tid == 320 && c < 12) {     // 8 power iters per chunk (96 total)
      #pragma unroll
      for (int it = 0; it < 8; ++it) {
        float wv[5];
        #pragma unroll
        for (int r = 0; r < 5; ++r) {
          float s = 0.f;
          #pragma unroll
          for (int cc = 0; cc < 5; ++cc) s += pL[r][cc]*pv[cc];
          wv[r] = s;
        }
        float s = fabsf(wv[0])+fabsf(wv[1])+fabsf(wv[2])+fabsf(wv[3])+fabsf(wv[4]);
        float inv = 1.f/s;
        #pragma unroll
        for (int r = 0; r < 5; ++r) pv[r] = wv[r]*inv;
      }
    }
    __syncthreads();                       // buf reads done
    if (tid < 320 && c + 1 < NCHK) {       // stage chunk c+1
      #pragma unroll
      for (int r = 0; r < 8; ++r) {
        const int L = kgx*16 + th*8 + r;
        buf[swz((2*q  )*2 + ksx, L)*4 + jwx] = cvtpk(xlo[r].x, xhi[r].x);
        buf[swz((2*q+1)*2 + ksx, L)*4 + jwx] = cvtpk(xlo[r].y, xhi[r].y);
      }
      #pragma unroll
      for (int e = 0; e < 5; ++e) {
        const int L = kgx*16 + gq;
        buf[5120 + swz((2*e  )*2 + ksx, L)*4 + jwx] = cvtpk(slo[e].x, shi[e].x);
        buf[5120 + swz((2*e+1)*2 + ksx, L)*4 + jwx] = cvtpk(slo[e].y, shi[e].y);
      }
    }
  }

  // ---- finalize k0 -> ck (mostly hidden under S writes)
  if (tid == 320) {
    float num = 0.f, den = 0.f;
    #pragma unroll
    for (int r = 0; r < 5; ++r) {
      float s = 0.f;
      #pragma unroll
      for (int cc = 0; cc < 5; ++cc) s += pL[r][cc]*pv[cc];
      num += pv[r]*s; den += pv[r]*pv[r];
    }
    const float lam = num/den;
    float Lt[5][5], T2[5][5];
    #pragma unroll
    for (int r = 0; r < 5; ++r)
      #pragma unroll
      for (int cc = 0; cc < 5; ++cc)
        Lt[r][cc] = 2.f*pL[r][cc]/lam - (r==cc ? 1.f : 0.f);
    #pragma unroll
    for (int r = 0; r < 5; ++r)
      #pragma unroll
      for (int cc = 0; cc < 5; ++cc) {
        float s = 0.f;
        #pragma unroll
        for (int j = 0; j < 5; ++j) s += Lt[r][j]*Lt[j][cc];
        T2[r][cc] = 2.f*s - (r==cc ? 1.f : 0.f);
      }
    #pragma unroll
    for (int p = 0; p < 10; ++p)
      #pragma unroll
      for (int nn = 0; nn < 10; ++nn) {
        const int m = (10*p+nn) % 25, r = m/5, cc = m%5;
        ck[0*100 + p*10+nn] = (r==cc ? 1.f : 0.f);
        ck[1*100 + p*10+nn] = Lt[r][cc];
        ck[2*100 + p*10+nn] = T2[r][cc];
      }
  }
  // ---- acc -> S (C layout: col=lane&15 (t), row=(lane>>4)*4+reg (p))
  if (tid < 320) {
    const int pg = (l >> 4) * 4;
    const int tl = l & 15;
    #pragma unroll
    for (int r = 0; r < 4; ++r) {
      const int p = pg + r;
      if (p < 10) {
        S[tl*120 + n0*12 + p] = acc0[r];
        S[tl*120 + n1*12 + p] = acc1[r];
      }
    }
  }
  __syncthreads();

  // ---- phase 2: out[t,b,n] = relu(sum_p S[n,p,t] * W[p,n,b])
  float* stg = (float*)buf;               // 10240 floats = 2 t x 512 b x 10
  for (int g = 0; g < 2; ++g) {
    const int b = g*512 + tid;
    float W[10][10];
    #pragma unroll
    for (int p = 0; p < 10; ++p) {
      const float th0 = theta[          p*NB + b];
      const float th1 = theta[10*NB  +  p*NB + b];
      const float th2 = theta[20*NB  +  p*NB + b];
      #pragma unroll
      for (int nn = 0; nn < 10; ++nn)
        W[p][nn] = ck[p*10+nn]*th0 + ck[100+p*10+nn]*th1 + ck[200+p*10+nn]*th2;
    }
    for (int tp = 0; tp < 8; ++tp) {
      float a0[10], a1[10];
      #pragma unroll
      for (int nn = 0; nn < 10; ++nn) {
        const float4 s0 = *(const float4*)(S + (2*tp)*120 + nn*12);
        const float4 s1 = *(const float4*)(S + (2*tp)*120 + nn*12 + 4);
        const float2 s2 = *(const float2*)(S + (2*tp)*120 + nn*12 + 8);
        a0[nn] = s0.x*W[0][nn] + s0.y*W[1][nn] + s0.z*W[2][nn] + s0.w*W[3][nn]
               + s1.x*W[4][nn] + s1.y*W[5][nn] + s1.z*W[6][nn] + s1.w*W[7][nn]
               + s2.x*W[8][nn] + s2.y*W[9][nn];
        const float4 u0 = *(const float4*)(S + (2*tp+1)*120 + nn*12);
        const float4 u1 = *(const float4*)(S + (2*tp+1)*120 + nn*12 + 4);
        const float2 u2 = *(const float2*)(S + (2*tp+1)*120 + nn*12 + 8);
        a1[nn] = u0.x*W[0][nn] + u0.y*W[1][nn] + u0.z*W[2][nn] + u0.w*W[3][nn]
               + u1.x*W[4][nn] + u1.y*W[5][nn] + u1.z*W[6][nn] + u1.w*W[7][nn]
               + u2.x*W[8][nn] + u2.y*W[9][nn];
      }
      __syncthreads();                    // prev stores done reading stg
      #pragma unroll
      for (int nn = 0; nn < 10; ++nn) {
        stg[       tid*10 + nn] = fmaxf(a0[nn], 0.f);
        stg[5120 + tid*10 + nn] = fmaxf(a1[nn], 0.f);
      }
      __syncthreads();
      const f32x4* sv = (const f32x4*)stg;
      f32x4* op0 = (f32x4*)(out + (size_t)(t0 + 2*tp)*(NB*NS) + g*5120);
      f32x4* op1 = (f32x4*)(out + (size_t)(t0 + 2*tp + 1)*(NB*NS) + g*5120);
      __builtin_nontemporal_store(sv[tid],        op0 + tid);
      __builtin_nontemporal_store(sv[tid + 512],  op0 + tid + 512);
      if (tid < 256)
        __builtin_nontemporal_store(sv[tid + 1024], op0 + tid + 1024);
      __builtin_nontemporal_store(sv[tid + 1280], op1 + tid);
      __builtin_nontemporal_store(sv[tid + 1792], op1 + tid + 512);
      if (tid < 256)
        __builtin_nontemporal_store(sv[tid + 2304], op1 + tid + 1024);
    }
  }
}

extern "C" void kernel_launch(void* const* d_in, const int* in_sizes, int n_in,
                              void* d_out, int out_size, void* d_ws, size_t ws_size,
                              hipStream_t stream) {
  const float* x   = (const float*)d_in[0];  // (4096,1024,10)
  const float* adj = (const float*)d_in[1];  // (5,5)
  const float* sa  = (const float*)d_in[2];  // (1024,10,10)
  const float* th  = (const float*)d_in[3];  // (3,10,1024)
  float* out = (float*)d_out;
  hipLaunchKernelGGL(fused_k, dim3(TLEN/16), dim3(512), 0, stream,
                     x, sa, adj, th, out);
}